// Round 11
// baseline (336.433 us; speedup 1.0000x reference)
//
#include <hip/hip_runtime.h>
#include <math.h>
#include <stdint.h>

typedef uint32_t u32; typedef uint64_t u64; typedef uint16_t u16; typedef int32_t i32;

#define BATCH 8
#define NA    261888      // anchors per batch = 32 segs * 8184
#define SEGS  32          // histcache blocks per batch
#define SEGCHUNK 8184     // elements per block
#define WCHUNK 2046       // elements per wave (4 waves/block)
#define SUBCAP 64         // cache slots per (block,wave) sub-segment (mean ~32)
#define NSUB  128         // sub-segments per batch = SEGS*4
#define TOPK  6000        // PRE_NMS_LIMIT (fallback only)
#define PROP  1000        // PROPOSAL_COUNT
#define TOP1  1024        // fast-path window = NMS width
#define TMPCAP 2048       // rank-scatter capacity (n>TMPCAP -> fb)
#define CACHEB 8192       // cache slots per batch (128 subsegs * 64)
#define FBMAX 16384       // fallback candidate capacity (~6.1K expected)
#define NW64  16          // u64 words per 1024-bit candidate bitmap
#define PSTATIC 0x3F7C0000u   // 0.984375f; cache = {bits >= PSTATIC}, mean 4092/batch

// ws layout — 1,740,928 B total. fbkeys region is fb-only. NO mask buffer:
// the NMS computes suppression predicates on the fly from LDS boxes.
#define OFF_FBK   0              // u64 fbkeys[8][16384]  = 1,048,576 (fb only)
#define OFF_CACHE 1048576        // u64 cache[8][8192]    =   524,288
#define OFF_CNT   1572864        // u32 cnt[8][128]       =     4,096
#define OFF_STAT  1576960        // u32 stat[8] (+pad)    =       128
#define OFF_BOX   1577088        // float4 boxes[8][1024] =   131,072
#define OFF_AREA  1708160        // float areas[8][1024]  =    32,768
#define WS_NEEDED 1740928

// ---------------- shared exact numerics -------------------------------------

// bit-faithful numpy fp32 decode (no FMA contraction; correctly-rounded exp)
__device__ __forceinline__ void decode_box(const float4 an, const float4 dl,
                                           float4& bx, float& ar) {
    float d0 = __fmul_rn(dl.x, 0.1f), d1 = __fmul_rn(dl.y, 0.1f);
    float d2 = __fmul_rn(dl.z, 0.2f), d3 = __fmul_rn(dl.w, 0.2f);
    float h = __fsub_rn(an.z, an.x), w = __fsub_rn(an.w, an.y);
    float cy = __fadd_rn(__fadd_rn(an.x, __fmul_rn(0.5f, h)), __fmul_rn(d0, h));
    float cx = __fadd_rn(__fadd_rn(an.y, __fmul_rn(0.5f, w)), __fmul_rn(d1, w));
    float h2 = __fmul_rn(h, (float)exp((double)d2));
    float w2 = __fmul_rn(w, (float)exp((double)d3));
    float y1 = __fsub_rn(cy, __fmul_rn(0.5f, h2));
    float x1 = __fsub_rn(cx, __fmul_rn(0.5f, w2));
    float y2 = __fadd_rn(y1, h2);
    float x2 = __fadd_rn(x1, w2);
    y1 = fminf(fmaxf(y1, 0.f), 1.f); x1 = fminf(fmaxf(x1, 0.f), 1.f);
    y2 = fminf(fmaxf(y2, 0.f), 1.f); x2 = fminf(fmaxf(x2, 0.f), 1.f);
    bx = make_float4(y1, x1, y2, x2);
    ar = __fmul_rn(__fsub_rn(y2, y1), __fsub_rn(x2, x1));
}

// suppress(i,j) <=> RN(inter/union) > 0.7f <=> inter >= ((double)0.7f+2^-25)*union
// (product <= 49 significant bits -> double compare EXACT incl. tie-to-even midpoint)
__device__ __forceinline__ bool sup_pred(const float4 bi, const float ai,
                                         const float4 bj, const float aj) {
    const double tmid = (double)0.7f + 0x1p-25;
    float yy1 = fmaxf(bi.x, bj.x), xx1 = fmaxf(bi.y, bj.y);
    float yy2 = fminf(bi.z, bj.z), xx2 = fminf(bi.w, bj.w);
    float ih = fmaxf(__fsub_rn(yy2, yy1), 0.f);
    float iw = fmaxf(__fsub_rn(xx2, xx1), 0.f);
    float inter = __fmul_rn(ih, iw);
    float uni = __fsub_rn(__fadd_rn(ai, aj), inter);
    return (uni > 0.f) && ((double)inter >= tmid * (double)uni);
}

// ---------------- kernel 1: single probs pass (r6-verbatim, proven) ----------
__global__ __launch_bounds__(256) void k_histcache(const float4* __restrict__ p4,
                                                   u64* __restrict__ cache,
                                                   u32* __restrict__ cnt) {
    const int b = blockIdx.y, seg = blockIdx.x;
    const int wave = threadIdx.x >> 6, lane = threadIdx.x & 63;
    const u64 lmask = (1ull << lane) - 1ull;
    const size_t fbase = ((size_t)b * NA + seg * SEGCHUNK + wave * WCHUNK) >> 1;
    const u32 abase = (u32)(seg * SEGCHUNK + wave * WCHUNK);
    u64* cseg = cache + (size_t)b * CACHEB + (seg * 4 + wave) * SUBCAP;
    u32 wOff = 0;
    #pragma unroll
    for (int it = 0; it < 16; ++it) {          // 1023 float4/wave: 15 full + 63 lanes
        int f = it * 64 + lane;
        bool ok = f < (WCHUNK / 2);
        u32 bitsA = 0, bitsB = 0;
        if (ok) {
            float4 v = p4[fbase + f];
            bitsA = __float_as_uint(v.y);      // anchor 2f score
            bitsB = __float_as_uint(v.w);      // anchor 2f+1 score
        }
        bool pA = ok && bitsA >= PSTATIC;
        bool pB = ok && bitsB >= PSTATIC;
        u64 mA = __ballot(pA);
        u64 mB = __ballot(pB);
        u32 cA = (u32)__popcll(mA);
        if (pA) {
            u32 slot = wOff + (u32)__popcll(mA & lmask);
            if (slot < SUBCAP) cseg[slot] = ((u64)(~bitsA) << 32) | (u64)(abase + 2 * f);
        }
        if (pB) {
            u32 slot = wOff + cA + (u32)__popcll(mB & lmask);
            if (slot < SUBCAP) cseg[slot] = ((u64)(~bitsB) << 32) | (u64)(abase + 2 * f + 1);
        }
        wOff += cA + (u32)__popcll(mB);
    }
    if (lane == 0) cnt[b * NSUB + seg * 4 + wave] = wOff;   // true count (>SUBCAP -> fb)
}

// ---------------- kernel 2: rank-1024 + decode (r6-verbatim, proven) ---------
__global__ __launch_bounds__(1024) void k_sortdec(const u64* __restrict__ cache,
                                                  const u32* __restrict__ cnt,
                                                  const float4* __restrict__ anchors,
                                                  const float4* __restrict__ bbox,
                                                  u32* __restrict__ stat_g,
                                                  float4* __restrict__ boxes,
                                                  float* __restrict__ areas) {
    __shared__ u32 hist[4096];     // counts, then reused as scatter arrival counters
    __shared__ u32 suffix[4096];   // suffix[b] = sum_{b'>b} hist[b']
    __shared__ u32 ps[256];
    __shared__ u32 psS[257];
    __shared__ u64 tmp[TMPCAP];
    __shared__ u32 scnt[NSUB];
    __shared__ u32 wq[4];
    __shared__ u32 sP, sN, sBin, stat;
    const int b = blockIdx.x;
    const int tid = threadIdx.x;
    const int lane = tid & 63, wv = tid >> 6;
    if (tid == 0) { stat = 1u; sBin = 0xFFFFFFFFu; }
    for (int i = tid; i < 4096; i += 1024) hist[i] = 0;
    __syncthreads();
    if (tid < NSUB) {
        u32 raw = cnt[b * NSUB + tid];
        scnt[tid] = raw > SUBCAP ? SUBCAP : raw;
        if (raw > SUBCAP) stat = 0u;           // cache dropped elements -> fb
    }
    __syncthreads();
    for (int t = tid; t < CACHEB; t += 1024) {
        int sub = t >> 6, off = t & (SUBCAP - 1);
        if (off < (int)scnt[sub]) {
            u32 bits = ~((u32)(cache[(size_t)b * CACHEB + t] >> 32));
            atomicAdd(&hist[(bits >> 6) & 0xFFFu], 1u);
        }
    }
    __syncthreads();
    if (tid < 256) {
        u32 su = 0;
        #pragma unroll
        for (int k = 0; k < 16; ++k) su += hist[tid * 16 + k];
        ps[tid] = su;
    }
    __syncthreads();
    {
        u32 v = (tid < 256) ? ps[tid] : 0u;
        #pragma unroll
        for (int d = 1; d < 64; d <<= 1) {
            u32 o = __shfl_down(v, d);
            if (lane + d < 64) v += o;         // v = sum ps[tid .. end-of-wave]
        }
        if (tid < 256 && lane == 0) wq[wv] = v;
        __syncthreads();
        if (tid < 256) {
            u32 add = 0;
            for (int q = wv + 1; q < 4; ++q) add += wq[q];
            psS[tid] = v + add;                // inclusive suffix over segments
        }
        if (tid == 0) psS[256] = 0u;
        __syncthreads();
    }
    {
        const int t4 = tid * 4;
        const int seg = tid >> 2;
        const int segEnd = seg * 16 + 15;
        u32 tail = 0;
        for (int bb = t4 + 4; bb <= segEnd; ++bb) tail += hist[bb];
        u32 h0 = hist[t4], h1 = hist[t4 + 1], h2 = hist[t4 + 2], h3 = hist[t4 + 3];
        u32 s3 = psS[seg + 1] + tail;
        u32 s2 = s3 + h3;
        u32 s1 = s2 + h2;
        u32 s0 = s1 + h1;
        suffix[t4] = s0; suffix[t4 + 1] = s1; suffix[t4 + 2] = s2; suffix[t4 + 3] = s3;
        if (s0 < TOP1 && s0 + h0 >= TOP1) sBin = (u32)t4;
        if (s1 < TOP1 && s1 + h1 >= TOP1) sBin = (u32)(t4 + 1);
        if (s2 < TOP1 && s2 + h2 >= TOP1) sBin = (u32)(t4 + 2);
        if (s3 < TOP1 && s3 + h3 >= TOP1) sBin = (u32)(t4 + 3);
    }
    __syncthreads();
    if (tid == 0) {
        if (sBin == 0xFFFFFFFFu) stat = 0u;    // M < 1024 -> fb
        else {
            sP = PSTATIC + (sBin << 6);        // count(bits>=sP) in [1024, 1023+occ]
            u32 n = suffix[sBin] + hist[sBin];
            sN = n;
            if (n > TMPCAP) stat = 0u;         // boundary-bin blowup -> fb
        }
    }
    __syncthreads();
    if (stat) {                                // uniform branch (stat stable here)
        for (int i = tid; i < 4096; i += 1024) hist[i] = 0;   // reuse as arrival cnts
        __syncthreads();
        const u32 P = sP;
        for (int t = tid; t < CACHEB; t += 1024) {
            int sub = t >> 6, off = t & (SUBCAP - 1);
            if (off < (int)scnt[sub]) {
                u64 key = cache[(size_t)b * CACHEB + t];
                u32 bits = ~((u32)(key >> 32));
                if (bits >= P) {
                    u32 bin = (bits >> 6) & 0xFFFu;
                    u32 arr = atomicAdd(&hist[bin], 1u);
                    tmp[suffix[bin] + arr] = key;   // slot < sN <= TMPCAP
                }
            }
        }
        __syncthreads();
        const u32 n = sN;
        for (u32 t = (u32)tid; t < n; t += 1024) {
            u64 key = tmp[t];
            u32 bits = ~((u32)(key >> 32));
            u32 bin = (bits >> 6) & 0xFFFu;
            u32 base = suffix[bin], len = hist[bin];
            u32 pos = base;                    // exact rank: higher bins + within-bin
            for (u32 q = base; q < base + len; ++q) pos += (tmp[q] < key) ? 1u : 0u;
            if (pos < TOP1) {
                u32 idx = (u32)key;
                float4 bx; float ar;
                decode_box(anchors[(size_t)b * NA + idx], bbox[(size_t)b * NA + idx], bx, ar);
                boxes[b * TOP1 + pos] = bx;    // n >= 1024 -> all 1024 slots written
                areas[b * TOP1 + pos] = ar;
            }
        }
    }
    if (tid == 0) stat_g[b] = stat;
}

// ---------------- kernel 3: mask-free one-sweep NMS (one block per batch) ----
// 8 blocks x 1024 thr. Boxes -> LDS; barrier-stepped Gauss-Seidel where step
// s's suppression words are computed ON THE FLY from LDS boxes: wave s builds
// its triangular 64x64 sub-block per-lane and resolves it by ballot fixed
// point; waves > s test ONLY the surviving columns of chunk s (bitset walk of
// ldsV[s]) with early exit once suppressed. No mask buffer, no fences, no
// register arrays (nothing to spill), ~58 KB LDS. Exact: earlier chunks' V
// are FINAL when read (strictly-lower-triangular system).
__global__ __launch_bounds__(1024) void k_nmsfly(const float4* __restrict__ boxes,
                                                 const float* __restrict__ areas,
                                                 const float2* __restrict__ p2,
                                                 const float4* __restrict__ bbox,
                                                 const float4* __restrict__ anchors,
                                                 const u32* __restrict__ stat_g,
                                                 u64* __restrict__ fbkeys,
                                                 float4* __restrict__ out) {
    __shared__ float4 sbox[TOP1];      // 16 KB
    __shared__ float  sarea[TOP1];     //  4 KB
    __shared__ u64 ldsV[NW64];
    __shared__ u32 wpre[NW64 + 1];
    const int b = blockIdx.x;
    const int tid = threadIdx.x;
    const int wave = tid >> 6, lane = tid & 63;
    const u32 stat = stat_g[b];        // uniform across block
    if (stat) {
        for (int t = tid; t < TOP1; t += 1024) {
            sbox[t] = boxes[b * TOP1 + t];
            sarea[t] = areas[b * TOP1 + t];
        }
        __syncthreads();
        const int i = tid;             // this thread's candidate row
        const float4 bi = sbox[i];
        const float  ai = sarea[i];
        u64 ext = 0;                   // nonzero once row i is suppressed (final)
        for (int s = 0; s < NW64; ++s) {
            if (wave == s) {
                // triangular word of own chunk: bit j (j<lane) = sup(i, s*64+j)
                u64 intern = 0;
                for (int j = 0; j < 63; ++j)   // wave-uniform bound; predicated
                    if (j < lane && sup_pred(bi, ai, sbox[(s << 6) + j], sarea[(s << 6) + j]))
                        intern |= (1ull << j);
                const bool extSup = (ext != 0ull);
                u64 v = ~0ull;
                for (int it = 0; it < 64; ++it) {      // <= chain depth, typ. ~4
                    bool alive = (!extSup) && ((intern & v) == 0ull);
                    u64 nv = __ballot(alive);
                    if (nv == v) break;                // stable == unique fixed point
                    v = nv;
                }
                if (lane == 0) ldsV[s] = v;
            }
            __syncthreads();                           // ldsV[s] now FINAL
            if (wave > s && ext == 0ull) {             // test survivors of chunk s
                u64 m = ldsV[s];
                while (m) {
                    int j = __ffsll((unsigned long long)m) - 1;
                    m &= m - 1;
                    if (sup_pred(bi, ai, sbox[(s << 6) + j], sarea[(s << 6) + j])) {
                        ext = 1ull;                    // dead forever; stop testing
                        break;
                    }
                }
            }
        }
        if (tid == 0) {
            u32 r = 0;
            #pragma unroll
            for (int c = 0; c < NW64; ++c) { wpre[c] = r; r += (u32)__popcll(ldsV[c]); }
            wpre[NW64] = r;
        }
        __syncthreads();
        const u32 Vt = wpre[NW64];
        if (Vt >= PROP) {                              // fast path (expected always)
            const int w = i >> 6, bit = i & 63;
            u64 vw = ldsV[w];
            bool isv = ((vw >> bit) & 1ull) != 0ull;
            u32 rank = wpre[w] + (u32)__popcll(vw & ((1ull << bit) - 1ull));
            if (isv && rank < PROP) out[b * PROP + rank] = sbox[i];
            return;                                    // Vt>=PROP: all ranks written
        }
    }
    // ---- exact fallback: self-contained redo of the reference computation ----
    const int i = tid;
    __shared__ float4 abox[PROP];
    __shared__ float  aar[PROP];
    __shared__ u32 fh[4096];
    __shared__ u32 fps[256];
    __shared__ u32 nsh, sP6;
    if (i == 0) nsh = 0;
    for (int z = i; z < 4096; z += 1024) fh[z] = 0;
    __syncthreads();
    for (int a = i; a < NA; a += 1024) {       // own coarse hist (bits[31:18])
        u32 bits = __float_as_uint(p2[(size_t)b * NA + a].y);
        atomicAdd(&fh[bits >> 18], 1u);
    }
    __syncthreads();
    if (i < 256) {
        u32 su = 0;
        for (int k = 0; k < 16; ++k) su += fh[i * 16 + k];
        fps[i] = su;
    }
    __syncthreads();
    if (i == 0) {                              // rank-TOPK coarse bin -> P6
        u32 acc = 0; int seg = 0;
        for (int t = 255; t >= 0; --t) { if (acc + fps[t] >= TOPK) { seg = t; break; } acc += fps[t]; }
        int b6 = seg * 16; u32 g6 = acc;
        for (int k = 15; k >= 0; --k) {
            u32 c = fh[seg * 16 + k];
            if (g6 + c >= TOPK) { b6 = seg * 16 + k; break; }
            g6 += c;
        }
        sP6 = (u32)b6 << 18;                   // count(bits>=sP6) in [6000,~6070]
    }
    __syncthreads();
    u32 P6 = sP6;
    for (int a = i; a < NA; a += 1024) {
        u32 bits = __float_as_uint(p2[(size_t)b * NA + a].y);
        if (bits >= P6) {
            u32 p = atomicAdd(&nsh, 1u);
            if (p < FBMAX) fbkeys[(size_t)b * FBMAX + p] = ((u64)(~bits) << 32) | (u64)a;
        }
    }
    __syncthreads();
    u32 n = nsh; if (n > FBMAX) n = FBMAX;     // ~6.1K expected; overflow impossible
    volatile u64* vk = (volatile u64*)(fbkeys + (size_t)b * FBMAX);
    for (int i2 = (int)n + i; i2 < FBMAX; i2 += 1024) vk[i2] = ~0ull;
    __syncthreads();
    for (int k = 2; k <= FBMAX; k <<= 1) {     // global-memory bitonic, exact order
        for (int j = k >> 1; j > 0; j >>= 1) {
            for (int p = i; p < FBMAX / 2; p += 1024) {
                int ii = ((p & ~(j - 1)) << 1) | (p & (j - 1));
                int l = ii | j;
                u64 a = vk[ii], c = vk[l];
                bool up = ((ii & k) == 0);
                if ((a > c) == up) { vk[ii] = c; vk[l] = a; }
            }
            __syncthreads();
        }
    }
    int acc_n = 0;
    int limit = (int)n < TOPK ? (int)n : TOPK;
    for (int t = 0; t < limit && acc_n < PROP; ++t) {
        u32 idx = (u32)vk[t];
        float4 bi2; float ai2;
        decode_box(anchors[(size_t)b * NA + idx], bbox[(size_t)b * NA + idx], bi2, ai2);
        int pred = 0;
        if (i < acc_n) pred = sup_pred(bi2, ai2, abox[i], aar[i]) ? 1 : 0;
        int any = __syncthreads_or(pred);
        if (!any) {
            if (i == 0) {
                abox[acc_n] = bi2; aar[acc_n] = ai2;
                out[b * PROP + acc_n] = bi2;
            }
            ++acc_n;
            __syncthreads();
        }
    }
    for (int t = acc_n + i; t < PROP; t += 1024)
        out[b * PROP + t] = make_float4(0.f, 0.f, 0.f, 0.f);
}

// ---------------- launch ----------------------------------------------------

extern "C" void kernel_launch(void* const* d_in, const int* in_sizes, int n_in,
                              void* d_out, int out_size, void* d_ws, size_t ws_size,
                              hipStream_t stream) {
    (void)in_sizes; (void)n_in; (void)out_size;
    if (ws_size < (size_t)WS_NEEDED) return;   // ws_size constant per process -> same work every call
    const float2* p2      = (const float2*)d_in[0];
    const float4* p4      = (const float4*)d_in[0];
    const float4* bbox    = (const float4*)d_in[1];
    const float4* anchors = (const float4*)d_in[2];
    float4* out = (float4*)d_out;

    char* ws = (char*)d_ws;
    u64* fbkeys  = (u64*)(ws + OFF_FBK);
    u64* cache   = (u64*)(ws + OFF_CACHE);
    u32* cnt     = (u32*)(ws + OFF_CNT);
    u32* stat_g  = (u32*)(ws + OFF_STAT);
    float4* boxes= (float4*)(ws + OFF_BOX);
    float* areas = (float*)(ws + OFF_AREA);

    dim3 ghc(SEGS, BATCH);
    k_histcache<<<ghc,   256, 0, stream>>>(p4, cache, cnt);
    k_sortdec  <<<BATCH, 1024, 0, stream>>>(cache, cnt, anchors, bbox, stat_g, boxes, areas);
    k_nmsfly   <<<BATCH, 1024, 0, stream>>>(boxes, areas, p2, bbox, anchors, stat_g, fbkeys, out);
}

// Round 12
// 135.469 us; speedup vs baseline: 2.4835x; 2.4835x over previous
//
#include <hip/hip_runtime.h>
#include <math.h>
#include <stdint.h>

typedef uint32_t u32; typedef uint64_t u64; typedef uint16_t u16; typedef int32_t i32;

#define BATCH 8
#define NA    261888      // anchors per batch = 32 segs * 8184
#define SEGS  32          // histcache blocks per batch
#define SEGCHUNK 8184     // elements per block
#define WCHUNK 2046       // elements per wave (4 waves/block)
#define SUBCAP 64         // cache slots per (block,wave) sub-segment (mean ~32)
#define NSUB  128         // sub-segments per batch = SEGS*4
#define TOPK  6000        // PRE_NMS_LIMIT (fallback only)
#define PROP  1000        // PROPOSAL_COUNT
#define TOP1  1024        // fast-path window = NMS width
#define TMPCAP 2048       // rank-scatter capacity (n>TMPCAP -> fb)
#define CACHEB 8192       // cache slots per batch (128 subsegs * 64)
#define FBMAX 16384       // fallback candidate capacity (~6.1K expected)
#define NW64  16          // u64 words per 1024-bit candidate bitmap
#define PSTATIC 0x3F7C0000u   // 0.984375f; cache = {bits >= PSTATIC}, mean 4092/batch

// ws layout — 2,789,632 B total. fbkeys region is fb-only.
// mask region: u64 mw[8][16][1024] — word-major TRANSPOSED (word w of row i at
// mw[b][w][i]); only the lower triangle (w <= i>>6) is ever written/read.
#define OFF_FBK   0              // u64 fbkeys[8][16384]  = 1,048,576 (fb only)
#define OFF_CACHE 1048576        // u64 cache[8][8192]    =   524,288
#define OFF_CNT   1572864        // u32 cnt[8][128]       =     4,096
#define OFF_STAT  1576960        // u32 stat[8] (+pad)    =       128
#define OFF_BOX   1577216        // float4 boxes[8][1024] =   131,072
#define OFF_AREA  1708288        // float areas[8][1024]  =    32,768
#define OFF_MASK  1741056        // u64 mw[8][16][1024]   = 1,048,576
#define WS_NEEDED 2789632

// ---------------- shared exact numerics -------------------------------------

// bit-faithful numpy fp32 decode (no FMA contraction; correctly-rounded exp)
__device__ __forceinline__ void decode_box(const float4 an, const float4 dl,
                                           float4& bx, float& ar) {
    float d0 = __fmul_rn(dl.x, 0.1f), d1 = __fmul_rn(dl.y, 0.1f);
    float d2 = __fmul_rn(dl.z, 0.2f), d3 = __fmul_rn(dl.w, 0.2f);
    float h = __fsub_rn(an.z, an.x), w = __fsub_rn(an.w, an.y);
    float cy = __fadd_rn(__fadd_rn(an.x, __fmul_rn(0.5f, h)), __fmul_rn(d0, h));
    float cx = __fadd_rn(__fadd_rn(an.y, __fmul_rn(0.5f, w)), __fmul_rn(d1, w));
    float h2 = __fmul_rn(h, (float)exp((double)d2));
    float w2 = __fmul_rn(w, (float)exp((double)d3));
    float y1 = __fsub_rn(cy, __fmul_rn(0.5f, h2));
    float x1 = __fsub_rn(cx, __fmul_rn(0.5f, w2));
    float y2 = __fadd_rn(y1, h2);
    float x2 = __fadd_rn(x1, w2);
    y1 = fminf(fmaxf(y1, 0.f), 1.f); x1 = fminf(fmaxf(x1, 0.f), 1.f);
    y2 = fminf(fmaxf(y2, 0.f), 1.f); x2 = fminf(fmaxf(x2, 0.f), 1.f);
    bx = make_float4(y1, x1, y2, x2);
    ar = __fmul_rn(__fsub_rn(y2, y1), __fsub_rn(x2, x1));
}

// suppress(i,j) <=> RN(inter/union) > 0.7f <=> inter >= ((double)0.7f+2^-25)*union
// (product <= 49 significant bits -> double compare EXACT incl. tie-to-even midpoint)
__device__ __forceinline__ bool sup_pred(const float4 bi, const float ai,
                                         const float4 bj, const float aj) {
    const double tmid = (double)0.7f + 0x1p-25;
    float yy1 = fmaxf(bi.x, bj.x), xx1 = fmaxf(bi.y, bj.y);
    float yy2 = fminf(bi.z, bj.z), xx2 = fminf(bi.w, bj.w);
    float ih = fmaxf(__fsub_rn(yy2, yy1), 0.f);
    float iw = fmaxf(__fsub_rn(xx2, xx1), 0.f);
    float inter = __fmul_rn(ih, iw);
    float uni = __fsub_rn(__fadd_rn(ai, aj), inter);
    return (uni > 0.f) && ((double)inter >= tmid * (double)uni);
}

// ---------------- phase 1: single probs pass (pure stream) -------------------
__global__ __launch_bounds__(256) void k_histcache(const float4* __restrict__ p4,
                                                   u64* __restrict__ cache,
                                                   u32* __restrict__ cnt) {
    const int b = blockIdx.y, seg = blockIdx.x;
    const int wave = threadIdx.x >> 6, lane = threadIdx.x & 63;
    const u64 lmask = (1ull << lane) - 1ull;
    const size_t fbase = ((size_t)b * NA + seg * SEGCHUNK + wave * WCHUNK) >> 1;
    const u32 abase = (u32)(seg * SEGCHUNK + wave * WCHUNK);
    u64* cseg = cache + (size_t)b * CACHEB + (seg * 4 + wave) * SUBCAP;
    u32 wOff = 0;
    #pragma unroll
    for (int it = 0; it < 16; ++it) {          // 1023 float4/wave: 15 full + 63 lanes
        int f = it * 64 + lane;
        bool ok = f < (WCHUNK / 2);
        u32 bitsA = 0, bitsB = 0;
        if (ok) {
            float4 v = p4[fbase + f];
            bitsA = __float_as_uint(v.y);      // anchor 2f score
            bitsB = __float_as_uint(v.w);      // anchor 2f+1 score
        }
        bool pA = ok && bitsA >= PSTATIC;
        bool pB = ok && bitsB >= PSTATIC;
        u64 mA = __ballot(pA);
        u64 mB = __ballot(pB);
        u32 cA = (u32)__popcll(mA);
        if (pA) {
            u32 slot = wOff + (u32)__popcll(mA & lmask);
            if (slot < SUBCAP) cseg[slot] = ((u64)(~bitsA) << 32) | (u64)(abase + 2 * f);
        }
        if (pB) {
            u32 slot = wOff + cA + (u32)__popcll(mB & lmask);
            if (slot < SUBCAP) cseg[slot] = ((u64)(~bitsB) << 32) | (u64)(abase + 2 * f + 1);
        }
        wOff += cA + (u32)__popcll(mB);
    }
    if (lane == 0) cnt[b * NSUB + seg * 4 + wave] = wOff;   // true count (>SUBCAP -> fb)
}

// ---------------- phase 2: rank-1024 by counting-rank scatter + decode -------
__global__ __launch_bounds__(1024) void k_sortdec(const u64* __restrict__ cache,
                                                  const u32* __restrict__ cnt,
                                                  const float4* __restrict__ anchors,
                                                  const float4* __restrict__ bbox,
                                                  u32* __restrict__ stat_g,
                                                  float4* __restrict__ boxes,
                                                  float* __restrict__ areas) {
    __shared__ u32 hist[4096];     // counts, then reused as scatter arrival counters
    __shared__ u32 suffix[4096];   // suffix[b] = sum_{b'>b} hist[b']
    __shared__ u32 ps[256];        // 16-bin segment sums
    __shared__ u32 psS[257];       // inclusive suffix-scan of ps; psS[256]=0
    __shared__ u64 tmp[TMPCAP];    // bin-segmented qualifying keys
    __shared__ u32 scnt[NSUB];
    __shared__ u32 wq[4];
    __shared__ u32 sP, sN, sBin, stat;
    const int b = blockIdx.x;
    const int tid = threadIdx.x;
    const int lane = tid & 63, wv = tid >> 6;
    if (tid == 0) { stat = 1u; sBin = 0xFFFFFFFFu; }
    for (int i = tid; i < 4096; i += 1024) hist[i] = 0;
    __syncthreads();
    if (tid < NSUB) {
        u32 raw = cnt[b * NSUB + tid];
        scnt[tid] = raw > SUBCAP ? SUBCAP : raw;
        if (raw > SUBCAP) stat = 0u;           // cache dropped elements -> fb
    }
    __syncthreads();
    for (int t = tid; t < CACHEB; t += 1024) {
        int sub = t >> 6, off = t & (SUBCAP - 1);
        if (off < (int)scnt[sub]) {
            u32 bits = ~((u32)(cache[(size_t)b * CACHEB + t] >> 32));
            atomicAdd(&hist[(bits >> 6) & 0xFFFu], 1u);
        }
    }
    __syncthreads();
    if (tid < 256) {
        u32 su = 0;
        #pragma unroll
        for (int k = 0; k < 16; ++k) su += hist[tid * 16 + k];
        ps[tid] = su;
    }
    __syncthreads();
    {
        u32 v = (tid < 256) ? ps[tid] : 0u;
        #pragma unroll
        for (int d = 1; d < 64; d <<= 1) {
            u32 o = __shfl_down(v, d);
            if (lane + d < 64) v += o;         // v = sum ps[tid .. end-of-wave]
        }
        if (tid < 256 && lane == 0) wq[wv] = v;
        __syncthreads();
        if (tid < 256) {
            u32 add = 0;
            for (int q = wv + 1; q < 4; ++q) add += wq[q];
            psS[tid] = v + add;                // inclusive suffix over segments
        }
        if (tid == 0) psS[256] = 0u;
        __syncthreads();
    }
    {
        const int t4 = tid * 4;
        const int seg = tid >> 2;
        const int segEnd = seg * 16 + 15;
        u32 tail = 0;
        for (int bb = t4 + 4; bb <= segEnd; ++bb) tail += hist[bb];
        u32 h0 = hist[t4], h1 = hist[t4 + 1], h2 = hist[t4 + 2], h3 = hist[t4 + 3];
        u32 s3 = psS[seg + 1] + tail;
        u32 s2 = s3 + h3;
        u32 s1 = s2 + h2;
        u32 s0 = s1 + h1;
        suffix[t4] = s0; suffix[t4 + 1] = s1; suffix[t4 + 2] = s2; suffix[t4 + 3] = s3;
        if (s0 < TOP1 && s0 + h0 >= TOP1) sBin = (u32)t4;
        if (s1 < TOP1 && s1 + h1 >= TOP1) sBin = (u32)(t4 + 1);
        if (s2 < TOP1 && s2 + h2 >= TOP1) sBin = (u32)(t4 + 2);
        if (s3 < TOP1 && s3 + h3 >= TOP1) sBin = (u32)(t4 + 3);
    }
    __syncthreads();
    if (tid == 0) {
        if (sBin == 0xFFFFFFFFu) stat = 0u;    // M < 1024 -> fb
        else {
            sP = PSTATIC + (sBin << 6);        // count(bits>=sP) in [1024, 1023+occ]
            u32 n = suffix[sBin] + hist[sBin];
            sN = n;
            if (n > TMPCAP) stat = 0u;         // boundary-bin blowup -> fb
        }
    }
    __syncthreads();
    if (stat) {                                // uniform branch (stat stable here)
        for (int i = tid; i < 4096; i += 1024) hist[i] = 0;   // reuse as arrival cnts
        __syncthreads();
        const u32 P = sP;
        for (int t = tid; t < CACHEB; t += 1024) {
            int sub = t >> 6, off = t & (SUBCAP - 1);
            if (off < (int)scnt[sub]) {
                u64 key = cache[(size_t)b * CACHEB + t];
                u32 bits = ~((u32)(key >> 32));
                if (bits >= P) {
                    u32 bin = (bits >> 6) & 0xFFFu;
                    u32 arr = atomicAdd(&hist[bin], 1u);
                    tmp[suffix[bin] + arr] = key;   // slot < sN <= TMPCAP
                }
            }
        }
        __syncthreads();
        const u32 n = sN;
        for (u32 t = (u32)tid; t < n; t += 1024) {
            u64 key = tmp[t];
            u32 bits = ~((u32)(key >> 32));
            u32 bin = (bits >> 6) & 0xFFFu;
            u32 base = suffix[bin], len = hist[bin];
            u32 pos = base;                    // exact rank: higher bins + within-bin
            for (u32 q = base; q < base + len; ++q) pos += (tmp[q] < key) ? 1u : 0u;
            if (pos < TOP1) {
                u32 idx = (u32)key;
                float4 bx; float ar;
                decode_box(anchors[(size_t)b * NA + idx], bbox[(size_t)b * NA + idx], bx, ar);
                boxes[b * TOP1 + pos] = bx;    // n >= 1024 -> all 1024 slots written
                areas[b * TOP1 + pos] = ar;
            }
        }
    }
    if (tid == 0) stat_g[b] = stat;
}

// ---------------- phase 3a: lower-triangle suppression mask ------------------
// one wave per row; only chunks c <= irow>>6 computed (lower triangle), stored
// word-major mw[b][w][i] so the NMS waves read coalesced u64 per 64 rows.
__global__ __launch_bounds__(256) void k_mask(const float4* __restrict__ boxes,
                                              const float* __restrict__ areas,
                                              u32* __restrict__ mw32) {
    const int b = blockIdx.y;
    const int wave = threadIdx.x >> 6, lane = threadIdx.x & 63;
    const int irow = blockIdx.x * 4 + wave;       // 256 blocks * 4 waves = 1024 rows
    const int cmax = irow >> 6;                   // lower triangle only
    u32* mt = mw32 + (size_t)b * (NW64 * TOP1 * 2);
    float4 bi = boxes[b * TOP1 + irow];
    float  ai = areas[b * TOP1 + irow];
    u32 myw = 0;                                  // lane 2w: lo32 of word w; 2w+1: hi32
    for (int c = 0; c <= cmax; ++c) {             // wave-uniform bound
        float4 bj = boxes[b * TOP1 + c * 64 + lane];
        float  aj = areas[b * TOP1 + c * 64 + lane];
        u64 word = __ballot(sup_pred(bi, ai, bj, aj));   // wave-uniform
        if (lane == 2 * c)     myw = (u32)word;
        if (lane == 2 * c + 1) myw = (u32)(word >> 32);
    }
    // u32 address of half h of u64 word w of row i: ((w<<10)+i)*2 + h
    if (lane < 2 * (cmax + 1))
        mt[((lane >> 1) << 11) + (irow << 1) + (lane & 1)] = myw;
}

// ---------------- phase 3b: exact one-sweep NMS (16-wave barrier-stepped) ----
// Strictly lower-triangular system -> block-sequential Gauss-Seidel is exact in
// one forward sweep of 16 chunks of 64. Wave c owns chunk c: its mask words are
// loaded upfront into a STATICALLY-indexed rr[16] (predicated w<=wave; all
// compile-time indices -> guaranteed VGPRs, no scratch).
// 16 barrier steps: at step s wave s resolves its 64x64 triangular sub-block
// via ballot fixed point (<= chain depth; stable == unique fixed point) and
// publishes ldsV[s]; every wave > s then folds one static rr[s] & ldsV[s].
__global__ __launch_bounds__(1024, 4) void k_nms(const u64* __restrict__ mw_all,
                                                 const float4* __restrict__ boxes,
                                                 const float2* __restrict__ p2,
                                                 const float4* __restrict__ bbox,
                                                 const float4* __restrict__ anchors,
                                                 const u32* __restrict__ stat_g,
                                                 u64* __restrict__ fbkeys,
                                                 float4* __restrict__ out) {
    __shared__ u64 ldsV[NW64];
    __shared__ u32 wpre[NW64 + 1];
    const int b = blockIdx.x;
    const int tid = threadIdx.x;
    const int wave = tid >> 6, lane = tid & 63;
    {
        const u64* mw = mw_all + (size_t)b * (NW64 * TOP1);
        const u64 lmask = (1ull << lane) - 1ull;
        // upfront coalesced loads, all indices static after unroll
        u64 rr[NW64];
        u64 intern = 0;
        #pragma unroll
        for (int w = 0; w < NW64; ++w) {
            u64 v = 0;
            if (w <= wave) v = mw[(w << 10) + (wave << 6) + lane];
            if (w == wave) intern = v & lmask;
            rr[w] = (w < wave) ? v : 0ull;
        }
        u64 ext = 0;
        #pragma unroll
        for (int s = 0; s < NW64; ++s) {
            if (wave == s) {
                const bool extSup = (ext != 0ull);
                u64 v = ~0ull;
                for (int it = 0; it < 64; ++it) {   // <= chain depth, typ. ~4
                    bool alive = (!extSup) && ((intern & v) == 0ull);
                    u64 nv = __ballot(alive);
                    if (nv == v) break;             // stable == unique fixed point
                    v = nv;
                }
                if (lane == 0) ldsV[s] = v;
            }
            __syncthreads();
            if (wave > s) ext |= rr[s] & ldsV[s];   // static indices -> registers
        }
    }
    if (tid == 0) {
        u32 r = 0;
        #pragma unroll
        for (int c = 0; c < NW64; ++c) { wpre[c] = r; r += (u32)__popcll(ldsV[c]); }
        wpre[NW64] = r;
    }
    __syncthreads();
    const u32 Vt = wpre[NW64];
    if (Vt >= PROP && stat_g[b] != 0u) {           // fast path (expected always)
        const int i = tid;
        const int w = i >> 6, bit = i & 63;
        u64 vw = ldsV[w];
        bool isv = ((vw >> bit) & 1ull) != 0ull;
        u32 rank = wpre[w] + (u32)__popcll(vw & ((1ull << bit) - 1ull));
        if (isv && rank < PROP) out[b * PROP + rank] = boxes[b * TOP1 + i];
        return;                                    // Vt>=PROP: all PROP ranks written
    }
    // ---- exact fallback: self-contained redo of the reference computation ----
    const int i = tid;
    __shared__ float4 abox[PROP];
    __shared__ float  aar[PROP];
    __shared__ u32 fh[4096];
    __shared__ u32 fps[256];
    __shared__ u32 nsh, sP6;
    if (i == 0) nsh = 0;
    for (int z = i; z < 4096; z += 1024) fh[z] = 0;
    __syncthreads();
    for (int a = i; a < NA; a += 1024) {           // own coarse hist (bits[31:18])
        u32 bits = __float_as_uint(p2[(size_t)b * NA + a].y);
        atomicAdd(&fh[bits >> 18], 1u);
    }
    __syncthreads();
    if (i < 256) {
        u32 su = 0;
        for (int k = 0; k < 16; ++k) su += fh[i * 16 + k];
        fps[i] = su;
    }
    __syncthreads();
    if (i == 0) {                                  // rank-TOPK coarse bin -> P6
        u32 acc = 0; int seg = 0;
        for (int t = 255; t >= 0; --t) { if (acc + fps[t] >= TOPK) { seg = t; break; } acc += fps[t]; }
        int b6 = seg * 16; u32 g6 = acc;
        for (int k = 15; k >= 0; --k) {
            u32 c = fh[seg * 16 + k];
            if (g6 + c >= TOPK) { b6 = seg * 16 + k; break; }
            g6 += c;
        }
        sP6 = (u32)b6 << 18;                       // count(bits>=sP6) in [6000,~6070]
    }
    __syncthreads();
    u32 P6 = sP6;
    for (int a = i; a < NA; a += 1024) {
        u32 bits = __float_as_uint(p2[(size_t)b * NA + a].y);
        if (bits >= P6) {
            u32 p = atomicAdd(&nsh, 1u);
            if (p < FBMAX) fbkeys[(size_t)b * FBMAX + p] = ((u64)(~bits) << 32) | (u64)a;
        }
    }
    __syncthreads();
    u32 n = nsh; if (n > FBMAX) n = FBMAX;         // ~6.1K expected; overflow impossible
    volatile u64* vk = (volatile u64*)(fbkeys + (size_t)b * FBMAX);
    for (int i2 = (int)n + i; i2 < FBMAX; i2 += 1024) vk[i2] = ~0ull;
    __syncthreads();
    for (int k = 2; k <= FBMAX; k <<= 1) {         // global-memory bitonic, exact order
        for (int j = k >> 1; j > 0; j >>= 1) {
            for (int p = i; p < FBMAX / 2; p += 1024) {
                int ii = ((p & ~(j - 1)) << 1) | (p & (j - 1));
                int l = ii | j;
                u64 a = vk[ii], c = vk[l];
                bool up = ((ii & k) == 0);
                if ((a > c) == up) { vk[ii] = c; vk[l] = a; }
            }
            __syncthreads();
        }
    }
    int acc_n = 0;
    int limit = (int)n < TOPK ? (int)n : TOPK;
    for (int t = 0; t < limit && acc_n < PROP; ++t) {
        u32 idx = (u32)vk[t];
        float4 bi2; float ai2;
        decode_box(anchors[(size_t)b * NA + idx], bbox[(size_t)b * NA + idx], bi2, ai2);
        int pred = 0;
        if (i < acc_n) pred = sup_pred(bi2, ai2, abox[i], aar[i]) ? 1 : 0;
        int any = __syncthreads_or(pred);
        if (!any) {
            if (i == 0) {
                abox[acc_n] = bi2; aar[acc_n] = ai2;
                out[b * PROP + acc_n] = bi2;
            }
            ++acc_n;
            __syncthreads();
        }
    }
    for (int t = acc_n + i; t < PROP; t += 1024)
        out[b * PROP + t] = make_float4(0.f, 0.f, 0.f, 0.f);
}

// ---------------- launch ----------------------------------------------------

extern "C" void kernel_launch(void* const* d_in, const int* in_sizes, int n_in,
                              void* d_out, int out_size, void* d_ws, size_t ws_size,
                              hipStream_t stream) {
    (void)in_sizes; (void)n_in; (void)out_size;
    if (ws_size < (size_t)WS_NEEDED) return;   // ws_size constant per process -> same work every call
    const float2* p2      = (const float2*)d_in[0];
    const float4* p4      = (const float4*)d_in[0];
    const float4* bbox    = (const float4*)d_in[1];
    const float4* anchors = (const float4*)d_in[2];
    float4* out = (float4*)d_out;

    char* ws = (char*)d_ws;
    u64* fbkeys  = (u64*)(ws + OFF_FBK);
    u64* cache   = (u64*)(ws + OFF_CACHE);
    u32* cnt     = (u32*)(ws + OFF_CNT);
    u32* stat_g  = (u32*)(ws + OFF_STAT);
    float4* boxes= (float4*)(ws + OFF_BOX);
    float* areas = (float*)(ws + OFF_AREA);
    u32* mw32    = (u32*)(ws + OFF_MASK);
    u64* mw64    = (u64*)(ws + OFF_MASK);

    dim3 ghc(SEGS, BATCH), gmask(TOP1 / 4, BATCH);
    k_histcache<<<ghc,   256, 0, stream>>>(p4, cache, cnt);
    k_sortdec  <<<BATCH, 1024, 0, stream>>>(cache, cnt, anchors, bbox, stat_g, boxes, areas);
    k_mask     <<<gmask, 256, 0, stream>>>(boxes, areas, mw32);
    k_nms      <<<BATCH, 1024, 0, stream>>>(mw64, boxes, p2, bbox, anchors, stat_g, fbkeys, out);
}